// Round 7
// baseline (115.862 us; speedup 1.0000x reference)
//
#include <hip/hip_runtime.h>

// SIR recurrence, R6: 2-deep dependency chain via algebraic re-fold.
// R5 confirmed chain-bound (solo-wave dep-VALU latency ~16cyc; 3-op chain
// = 54.5 cyc/step; instruction-count changes are invisible). This round
// shortens the chain 3 -> 2 (the ONLY remaining lever):
//   nu = fma(u, fma(gamma, v, L), delta)      == L*u + gamma*u*v + delta
//   nv = fma(v, fma(-gamma, u, 1), -delta)    == v - gamma*u*v - delta
// Critical cycle u -> g -> v' -> f' -> u'' : 2 dependent ops/step.
// NOTE: this breaks the bit-exact FP sequence (absmax was 0.0 in R1-R5);
// expected absmax ~1e-4..1e-2 from rounding random-walk over 2047 steps.
// If validation fails: revert to R5 (that structure sits on the frozen-
// sequence latency floor).
//
// Everything else is the proven R5 structure: lane 0 serial, 4 global
// stores/step (hidden in chain stalls), helpers write col-4 zeros and
// retire, no LDS, no barriers.

__global__ __launch_bounds__(256) void sir_kernel(
    const float* __restrict__ x, const float* __restrict__ w2p,
    const float* __restrict__ w3p, const float* __restrict__ b3p,
    const float* __restrict__ w4p, const int* __restrict__ np,
    float* __restrict__ out) {
  const int n = *np;
  const int rows = n - 1;
  const int tid = threadIdx.x;

  if (tid != 0) {
    // col-4 zeros (d_out re-poisoned to 0xAA before every launch)
    for (int i = tid - 1; i < rows; i += 255) out[5 * i + 4] = 0.0f;
    return;
  }

  const float w2 = *w2p, w3 = *w3p, b3 = *b3p, w4 = *w4p;
  const float w2sq   = w2 * w2;
  const float w4sq   = w4 * w4;
  const float L      = 1.0f - w2sq - w4sq;
  const float gamma  = (w3 * w3) / 1000.0f;
  const float mgamma = -gamma;
  const float delta  = fmaf(w3, b3, b3);
  const float mdelta = -delta;

  float u = x[0], s1 = x[1], v = x[2], s3 = x[3];
  float* __restrict__ p = out;

  if (rows == 2047) {
#pragma unroll 23
    for (int i = 0; i < 2047; ++i) {
      const float f  = fmaf(gamma, v, L);     // dep: v
      const float g  = fmaf(mgamma, u, 1.0f); // dep: u   (parallel with f)
      const float nu = fmaf(u, f, delta);     // dep: f   -> chain depth 2
      const float nv = fmaf(v, g, mdelta);    // dep: g   -> chain depth 2
      s1 = fmaf(w2sq, u, s1);                 // off-chain
      s3 = fmaf(w4sq, u, s3);                 // off-chain
      u = nu;
      v = nv;
      p[0] = nu;
      p[1] = s1;
      p[2] = nv;
      p[3] = s3;
      p += 5;
    }
  } else {
#pragma unroll 4
    for (int i = 0; i < rows; ++i) {
      const float f  = fmaf(gamma, v, L);
      const float g  = fmaf(mgamma, u, 1.0f);
      const float nu = fmaf(u, f, delta);
      const float nv = fmaf(v, g, mdelta);
      s1 = fmaf(w2sq, u, s1);
      s3 = fmaf(w4sq, u, s3);
      u = nu;
      v = nv;
      p[0] = nu;
      p[1] = s1;
      p[2] = nv;
      p[3] = s3;
      p += 5;
    }
  }
}

extern "C" void kernel_launch(void* const* d_in, const int* in_sizes, int n_in,
                              void* d_out, int out_size, void* d_ws, size_t ws_size,
                              hipStream_t stream) {
  const float* x   = (const float*)d_in[0];
  const float* w2  = (const float*)d_in[1];
  const float* w3  = (const float*)d_in[2];
  const float* b3  = (const float*)d_in[3];
  const float* w4  = (const float*)d_in[4];
  const int*   n   = (const int*)d_in[5];
  float* out = (float*)d_out;
  sir_kernel<<<1, 256, 0, stream>>>(x, w2, w3, b3, w4, n, out);
}

// Round 8
// 114.195 us; speedup vs baseline: 1.0146x; 1.0146x over previous
//
#include <hip/hip_runtime.h>

// SIR recurrence, R7: 2-deep chain (R6 math, absmax proven 0.0) + MANUAL
// static schedule. R6 post-mortem: solo wave is in-order, so the compiler's
// instruction PLACEMENT sets the time; it exposed 4 dep-stalls/step (73cyc)
// instead of 2 (D~18cyc). Fix: hand-pipelined unroll-2 with A/B register
// sets, stores lagging one stage (stored values always >=D old), and
// sched_barrier(0) fences pinning {f,g} | {s1,s3,stores} | {u',v'} groups
// so independent work sits INSIDE the stall windows.
//
//   f  = fma(gamma, v, L)     g  = fma(-gamma, u, 1)
//   u' = fma(u, f, delta)     v' = fma(v, g, -delta)
//   s1' = fma(w2sq, u, s1)    s3' = fma(w4sq, u, s3)

#define SB() __builtin_amdgcn_sched_barrier(0)

__global__ __launch_bounds__(256) void sir_kernel(
    const float* __restrict__ x, const float* __restrict__ w2p,
    const float* __restrict__ w3p, const float* __restrict__ b3p,
    const float* __restrict__ w4p, const int* __restrict__ np,
    float* __restrict__ out) {
  const int n = *np;
  const int rows = n - 1;
  const int tid = threadIdx.x;

  if (tid != 0) {
    // col-4 zeros (d_out re-poisoned to 0xAA before every launch)
    for (int i = tid - 1; i < rows; i += 255) out[5 * i + 4] = 0.0f;
    return;
  }

  const float w2 = *w2p, w3 = *w3p, b3 = *b3p, w4 = *w4p;
  const float w2sq   = w2 * w2;
  const float w4sq   = w4 * w4;
  const float L      = 1.0f - w2sq - w4sq;
  const float gamma  = (w3 * w3) / 1000.0f;
  const float mgamma = -gamma;
  const float delta  = fmaf(w3, b3, b3);
  const float mdelta = -delta;

  const float u0 = x[0], s10 = x[1], v0 = x[2], s30 = x[3];

  if (rows == 2047) {
    // ---- prologue: step 0 -> A regs hold row 0 ----
    const float fA0 = fmaf(gamma, v0, L);
    const float gA0 = fmaf(mgamma, u0, 1.0f);
    float uA  = fmaf(u0, fA0, delta);
    float vA  = fmaf(v0, gA0, mdelta);
    float s1A = fmaf(w2sq, u0, s10);
    float s3A = fmaf(w4sq, u0, s30);

    float* __restrict__ p = out;
    // steps 1..2046 as 1023 A->B->A pairs; stores lag one stage
    for (int k = 0; k < 1023; ++k) {
      // -- body1: compute row 2k+1 into B; store row 2k from A --
      const float fB = fmaf(gamma, vA, L);
      const float gB = fmaf(mgamma, uA, 1.0f);
      SB();
      const float s1B = fmaf(w2sq, uA, s1A);
      const float s3B = fmaf(w4sq, uA, s3A);
      p[0] = uA;  p[1] = s1A;  p[2] = vA;  p[3] = s3A;
      SB();
      const float uB = fmaf(uA, fB, delta);
      const float vB = fmaf(vA, gB, mdelta);
      SB();
      // -- body2: compute row 2k+2 into A; store row 2k+1 from B --
      const float fA = fmaf(gamma, vB, L);
      const float gA = fmaf(mgamma, uB, 1.0f);
      SB();
      s1A = fmaf(w2sq, uB, s1B);
      s3A = fmaf(w4sq, uB, s3B);
      p[5] = uB;  p[6] = s1B;  p[7] = vB;  p[8] = s3B;
      SB();
      uA = fmaf(uB, fA, delta);
      vA = fmaf(vB, gA, mdelta);
      SB();
      p += 10;
    }
    // ---- epilogue: store row 2046 ----
    p[0] = uA;  p[1] = s1A;  p[2] = vA;  p[3] = s3A;
  } else {
    // generic fallback, same FP op sequence
    float u = u0, s1 = s10, v = v0, s3 = s30;
    float* __restrict__ p = out;
#pragma unroll 4
    for (int i = 0; i < rows; ++i) {
      const float f  = fmaf(gamma, v, L);
      const float g  = fmaf(mgamma, u, 1.0f);
      const float nu = fmaf(u, f, delta);
      const float nv = fmaf(v, g, mdelta);
      s1 = fmaf(w2sq, u, s1);
      s3 = fmaf(w4sq, u, s3);
      u = nu;
      v = nv;
      p[0] = nu; p[1] = s1; p[2] = nv; p[3] = s3;
      p += 5;
    }
  }
}

extern "C" void kernel_launch(void* const* d_in, const int* in_sizes, int n_in,
                              void* d_out, int out_size, void* d_ws, size_t ws_size,
                              hipStream_t stream) {
  const float* x   = (const float*)d_in[0];
  const float* w2  = (const float*)d_in[1];
  const float* w3  = (const float*)d_in[2];
  const float* b3  = (const float*)d_in[3];
  const float* w4  = (const float*)d_in[4];
  const int*   n   = (const int*)d_in[5];
  float* out = (float*)d_out;
  sir_kernel<<<1, 256, 0, stream>>>(x, w2, w3, b3, w4, n, out);
}